// Round 1
// baseline (443.674 us; speedup 1.0000x reference)
//
#include <hip/hip_runtime.h>
#include <hip/hip_bf16.h>
#include <math.h>

#define NE 32        // experts
#define H 512
#define H2 1024      // 2H
#define NTOK 2048    // B*S
#define CAP 2048     // per-expert token capacity (worst case)

typedef __attribute__((ext_vector_type(8))) short bf16x8;
typedef __attribute__((ext_vector_type(4))) float f32x4;
typedef unsigned int uint;
typedef unsigned short ushort;

__device__ __forceinline__ uint bf16r(float f) {
    uint u = __float_as_uint(f);
    return (u + 0x7FFFu + ((u >> 16) & 1u)) >> 16;   // RNE
}
__device__ __forceinline__ uint pack_bf16(float a, float b) {
    return bf16r(a) | (bf16r(b) << 16);
}

// ---------------------------------------------------------------------------
// Kernel 1: gating — logits, softmax, top-4, renorm, expert lists, x->bf16
// one wave per token; block=256 (4 tokens), grid = NTOK/4
// ---------------------------------------------------------------------------
__global__ __launch_bounds__(256) void gating_kernel(
    const float* __restrict__ x, const float* __restrict__ gate_w,
    int* __restrict__ cnt, int* __restrict__ listTok, int* __restrict__ listPair,
    float* __restrict__ listW, ushort* __restrict__ xbf)
{
    const int wave = threadIdx.x >> 6;
    const int lane = threadIdx.x & 63;
    const int t = blockIdx.x * 4 + wave;
    const int e = lane & 31;
    const int half = lane >> 5;

    const float4* xr = (const float4*)(x + (size_t)t * H + half * 256);
    const float4* gr = (const float4*)(gate_w + (size_t)e * H + half * 256);
    float acc = 0.f;
#pragma unroll 8
    for (int i = 0; i < 64; ++i) {
        float4 a = xr[i], b = gr[i];
        acc += a.x * b.x + a.y * b.y + a.z * b.z + a.w * b.w;
    }
    acc += __shfl_xor(acc, 32);   // combine halves: all lanes hold logit[e]

    // softmax over 32 experts (duplicated across lane groups)
    float mx = acc;
#pragma unroll
    for (int m = 16; m >= 1; m >>= 1) mx = fmaxf(mx, __shfl_xor(mx, m));
    float p = __expf(acc - mx);
    float s = p;
#pragma unroll
    for (int m = 16; m >= 1; m >>= 1) s += __shfl_xor(s, m);
    float prob = p / s;

    // top-4 (ties -> lowest index, matches lax.top_k)
    int   selk[4];
    float wk[4];
    float sum4 = 0.f;
#pragma unroll
    for (int k = 0; k < 4; ++k) {
        float v = prob; int idx = e;
#pragma unroll
        for (int m = 16; m >= 1; m >>= 1) {
            float v2 = __shfl_xor(v, m);
            int   i2 = __shfl_xor(idx, m);
            if (v2 > v || (v2 == v && i2 < idx)) { v = v2; idx = i2; }
        }
        selk[k] = idx; wk[k] = v; sum4 += v;
        if (e == idx) prob = -1.f;
    }

    if (lane == 0) {
#pragma unroll
        for (int k = 0; k < 4; ++k) {
            int ex = selk[k];
            int pos = atomicAdd(&cnt[ex], 1);
            listTok [ex * CAP + pos] = t;
            listPair[ex * CAP + pos] = t * 4 + k;
            listW   [ex * CAP + pos] = wk[k] / sum4;
        }
    }

    // convert this token's x row to bf16 (8 elems per lane)
    const float4* xrow4 = (const float4*)(x + (size_t)t * H);
    float4 a0 = xrow4[lane * 2];
    float4 a1 = xrow4[lane * 2 + 1];
    uint4 o;
    o.x = pack_bf16(a0.x, a0.y);
    o.y = pack_bf16(a0.z, a0.w);
    o.z = pack_bf16(a1.x, a1.y);
    o.w = pack_bf16(a1.z, a1.w);
    ((uint4*)(xbf + (size_t)t * H))[lane] = o;
}

// ---------------------------------------------------------------------------
// Kernel 2: grouped GEMM1 + SiLU*up, scaled by combine weight.
// block = (expert e, token-tile mt of 128, chunk ch of 128 cols of 2H)
// hidden[pair][2H] (bf16) = silu(X@wg^T) * (X@wu^T) * w_pair
// ---------------------------------------------------------------------------
__global__ __launch_bounds__(256) void moe_gemm1(
    const float* __restrict__ w_gate, const float* __restrict__ w_up,
    const ushort* __restrict__ xbf, const int* __restrict__ cnt,
    const int* __restrict__ listTok, const int* __restrict__ listPair,
    const float* __restrict__ listW, ushort* __restrict__ hidden)
{
    const int e  = blockIdx.x;
    const int mt = blockIdx.y;
    const int ch = blockIdx.z;
    const int count = cnt[e];
    const int m0 = mt * 128;
    if (m0 >= count) return;

    __shared__ ushort Xs[128 * 72];
    __shared__ ushort Gs[128 * 72];
    __shared__ ushort Us[128 * 72];

    const int tid  = threadIdx.x;
    const int lane = tid & 63;
    const int wave = tid >> 6;
    const int l15  = lane & 15;
    const int quad = lane >> 4;

    // staging map: 2 threads per row, 32 elems each
    const int sr = tid >> 1;
    const int sh = tid & 1;
    const int slot = m0 + sr;
    const int tok  = (slot < count) ? listTok[e * CAP + slot] : 0;
    const ushort* xrow = xbf + (size_t)tok * H;
    const float*  grow = w_gate + ((size_t)e * H2 + (size_t)(ch * 128 + sr)) * H;
    const float*  urow = w_up   + ((size_t)e * H2 + (size_t)(ch * 128 + sr)) * H;

    f32x4 accg[2][8], accu[2][8];
    const f32x4 fz = {0.f, 0.f, 0.f, 0.f};
#pragma unroll
    for (int mi = 0; mi < 2; ++mi)
#pragma unroll
        for (int ni = 0; ni < 8; ++ni) { accg[mi][ni] = fz; accu[mi][ni] = fz; }

    for (int k0 = 0; k0 < H; k0 += 64) {
        // global loads first (latency)
        const uint4* xs = (const uint4*)(xrow + k0 + sh * 32);
        uint4 xv[4];
#pragma unroll
        for (int i = 0; i < 4; ++i) xv[i] = xs[i];
        const float4* gp = (const float4*)(grow + k0 + sh * 32);
        const float4* up = (const float4*)(urow + k0 + sh * 32);
        float4 g[8], u[8];
#pragma unroll
        for (int i = 0; i < 8; ++i) { g[i] = gp[i]; u[i] = up[i]; }

        __syncthreads();   // previous iter's LDS reads done

        uint4* xl = (uint4*)(Xs + sr * 72 + sh * 32);
#pragma unroll
        for (int i = 0; i < 4; ++i) xl[i] = xv[i];
        uint4* gl = (uint4*)(Gs + sr * 72 + sh * 32);
        uint4* ul = (uint4*)(Us + sr * 72 + sh * 32);
#pragma unroll
        for (int i = 0; i < 4; ++i) {
            uint4 w;
            w.x = pack_bf16(g[2*i].x,   g[2*i].y);
            w.y = pack_bf16(g[2*i].z,   g[2*i].w);
            w.z = pack_bf16(g[2*i+1].x, g[2*i+1].y);
            w.w = pack_bf16(g[2*i+1].z, g[2*i+1].w);
            gl[i] = w;
            uint4 v;
            v.x = pack_bf16(u[2*i].x,   u[2*i].y);
            v.y = pack_bf16(u[2*i].z,   u[2*i].w);
            v.z = pack_bf16(u[2*i+1].x, u[2*i+1].y);
            v.w = pack_bf16(u[2*i+1].z, u[2*i+1].w);
            ul[i] = v;
        }
        __syncthreads();

#pragma unroll
        for (int ks = 0; ks < 2; ++ks) {
            bf16x8 af[2];
            af[0] = *(const bf16x8*)(Xs + (wave * 32 +      l15) * 72 + ks * 32 + quad * 8);
            af[1] = *(const bf16x8*)(Xs + (wave * 32 + 16 + l15) * 72 + ks * 32 + quad * 8);
#pragma unroll
            for (int ni = 0; ni < 8; ++ni) {
                bf16x8 bg = *(const bf16x8*)(Gs + (ni * 16 + l15) * 72 + ks * 32 + quad * 8);
                bf16x8 bu = *(const bf16x8*)(Us + (ni * 16 + l15) * 72 + ks * 32 + quad * 8);
                accg[0][ni] = __builtin_amdgcn_mfma_f32_16x16x32_bf16(af[0], bg, accg[0][ni], 0, 0, 0);
                accg[1][ni] = __builtin_amdgcn_mfma_f32_16x16x32_bf16(af[1], bg, accg[1][ni], 0, 0, 0);
                accu[0][ni] = __builtin_amdgcn_mfma_f32_16x16x32_bf16(af[0], bu, accu[0][ni], 0, 0, 0);
                accu[1][ni] = __builtin_amdgcn_mfma_f32_16x16x32_bf16(af[1], bu, accu[1][ni], 0, 0, 0);
            }
        }
    }

    // epilogue: hidden = silu(g)*u * w_pair, bf16
#pragma unroll
    for (int mi = 0; mi < 2; ++mi) {
        const int mrow = wave * 32 + mi * 16 + quad * 4;
#pragma unroll
        for (int r = 0; r < 4; ++r) {
            const int slot2 = m0 + mrow + r;
            if (slot2 < count) {
                const int   pair = listPair[e * CAP + slot2];
                const float wgt  = listW  [e * CAP + slot2];
                ushort* hrow = hidden + (size_t)pair * H2 + ch * 128;
#pragma unroll
                for (int ni = 0; ni < 8; ++ni) {
                    float gv = accg[mi][ni][r];
                    float uv = accu[mi][ni][r];
                    float hv = (gv / (1.f + __expf(-gv))) * uv * wgt;
                    hrow[ni * 16 + l15] = (ushort)bf16r(hv);
                }
            }
        }
    }
}

// ---------------------------------------------------------------------------
// Kernel 3: grouped GEMM2: out[tok] += hidden[pair] @ wd^T  (atomicAdd fp32)
// block = (expert e, token-tile mt of 128, chunk ch of 128 cols of H)
// ---------------------------------------------------------------------------
__global__ __launch_bounds__(256) void moe_gemm2(
    const float* __restrict__ w_down, const ushort* __restrict__ hidden,
    const int* __restrict__ cnt, const int* __restrict__ listTok,
    const int* __restrict__ listPair, float* __restrict__ out)
{
    const int e  = blockIdx.x;
    const int mt = blockIdx.y;
    const int ch = blockIdx.z;
    const int count = cnt[e];
    const int m0 = mt * 128;
    if (m0 >= count) return;

    __shared__ ushort As[128 * 72];
    __shared__ ushort Bs[128 * 72];

    const int tid  = threadIdx.x;
    const int lane = tid & 63;
    const int wave = tid >> 6;
    const int l15  = lane & 15;
    const int quad = lane >> 4;

    const int sr = tid >> 1;
    const int sh = tid & 1;
    const int slot = m0 + sr;
    const int pair = (slot < count) ? listPair[e * CAP + slot] : 0;
    const ushort* arow = hidden + (size_t)pair * H2;
    const float*  brow = w_down + ((size_t)e * H + (size_t)(ch * 128 + sr)) * H2;

    f32x4 acc[2][8];
    const f32x4 fz = {0.f, 0.f, 0.f, 0.f};
#pragma unroll
    for (int mi = 0; mi < 2; ++mi)
#pragma unroll
        for (int ni = 0; ni < 8; ++ni) acc[mi][ni] = fz;

    for (int k0 = 0; k0 < H2; k0 += 64) {
        const uint4* ap = (const uint4*)(arow + k0 + sh * 32);
        uint4 av[4];
#pragma unroll
        for (int i = 0; i < 4; ++i) av[i] = ap[i];
        const float4* bp = (const float4*)(brow + k0 + sh * 32);
        float4 b[8];
#pragma unroll
        for (int i = 0; i < 8; ++i) b[i] = bp[i];

        __syncthreads();

        uint4* al = (uint4*)(As + sr * 72 + sh * 32);
#pragma unroll
        for (int i = 0; i < 4; ++i) al[i] = av[i];
        uint4* bl = (uint4*)(Bs + sr * 72 + sh * 32);
#pragma unroll
        for (int i = 0; i < 4; ++i) {
            uint4 w;
            w.x = pack_bf16(b[2*i].x,   b[2*i].y);
            w.y = pack_bf16(b[2*i].z,   b[2*i].w);
            w.z = pack_bf16(b[2*i+1].x, b[2*i+1].y);
            w.w = pack_bf16(b[2*i+1].z, b[2*i+1].w);
            bl[i] = w;
        }
        __syncthreads();

#pragma unroll
        for (int ks = 0; ks < 2; ++ks) {
            bf16x8 af[2];
            af[0] = *(const bf16x8*)(As + (wave * 32 +      l15) * 72 + ks * 32 + quad * 8);
            af[1] = *(const bf16x8*)(As + (wave * 32 + 16 + l15) * 72 + ks * 32 + quad * 8);
#pragma unroll
            for (int ni = 0; ni < 8; ++ni) {
                bf16x8 bf = *(const bf16x8*)(Bs + (ni * 16 + l15) * 72 + ks * 32 + quad * 8);
                acc[0][ni] = __builtin_amdgcn_mfma_f32_16x16x32_bf16(af[0], bf, acc[0][ni], 0, 0, 0);
                acc[1][ni] = __builtin_amdgcn_mfma_f32_16x16x32_bf16(af[1], bf, acc[1][ni], 0, 0, 0);
            }
        }
    }

    // epilogue: atomicAdd into out (hidden already carries combine weight)
#pragma unroll
    for (int mi = 0; mi < 2; ++mi) {
        const int mrow = wave * 32 + mi * 16 + quad * 4;
#pragma unroll
        for (int r = 0; r < 4; ++r) {
            const int slot2 = m0 + mrow + r;
            if (slot2 < count) {
                const int tok = listTok[e * CAP + slot2];
                float* orow = out + (size_t)tok * H + ch * 128;
#pragma unroll
                for (int ni = 0; ni < 8; ++ni) {
                    atomicAdd(&orow[ni * 16 + l15], acc[mi][ni][r]);
                }
            }
        }
    }
}

// ---------------------------------------------------------------------------
extern "C" void kernel_launch(void* const* d_in, const int* in_sizes, int n_in,
                              void* d_out, int out_size, void* d_ws, size_t ws_size,
                              hipStream_t stream)
{
    (void)in_sizes; (void)n_in; (void)ws_size;
    const float* x      = (const float*)d_in[0];
    const float* gate_w = (const float*)d_in[1];
    const float* w_gate = (const float*)d_in[2];
    const float* w_up   = (const float*)d_in[3];
    const float* w_down = (const float*)d_in[4];
    // d_in[5] = top_k (fixed at 4)

    char* ws = (char*)d_ws;
    int*    cnt      = (int*)ws;                                   // 32 ints (128 B slot)
    int*    listTok  = (int*)(ws + 128);                           // E*CAP
    int*    listPair = (int*)(ws + 128 + (size_t)NE * CAP * 4);
    float*  listW    = (float*)(ws + 128 + (size_t)NE * CAP * 8);
    ushort* xbf      = (ushort*)(ws + 128 + (size_t)NE * CAP * 12);
    ushort* hidden   = (ushort*)(ws + 128 + (size_t)NE * CAP * 12 + (size_t)NTOK * H * 2);
    // total ws use: 128 + 768KB + 2MB + 16MB ≈ 19MB

    hipMemsetAsync(cnt, 0, 128, stream);
    hipMemsetAsync(d_out, 0, (size_t)out_size * sizeof(float), stream);

    gating_kernel<<<NTOK / 4, 256, 0, stream>>>(x, gate_w, cnt, listTok, listPair, listW, xbf);
    moe_gemm1<<<dim3(NE, 16, 8), 256, 0, stream>>>(w_gate, w_up, xbf, cnt, listTok,
                                                   listPair, listW, hidden);
    moe_gemm2<<<dim3(NE, 16, 4), 256, 0, stream>>>(w_down, hidden, cnt, listTok,
                                                   listPair, (float*)d_out);
}